// Round 6
// baseline (1579.676 us; speedup 1.0000x reference)
//
#include <hip/hip_runtime.h>
#include <math.h>

#define NN 1048576
#define EE 4194304
#define NBUCK 256
#define BNODES 4096          // nodes per bucket (NN / NBUCK)
#define CAP 20480            // bucket edge capacity (mean 16384, sigma~128)
#define NCLS 64              // degree classes 0..63 (63 = catch-all)
constexpr float BN_EPS = 1e-5f;

typedef _Float16 half8  __attribute__((ext_vector_type(8)));

// ---- workspace layout (bytes), high-water 121 MB (<=128 MB validated in R1) ----
#define OFF_SSRC    0u           // 20 MB: original-CSR src ids (bucket layout w/ gaps)
#define OFF_ROWPTR  20971520u    // 4 MB
#define OFF_ROWEND  25165824u    // 4 MB
#define OFF_MISC    29360128u    // 1 MB: cursor@0, stats@4096, classcnt@65536, classcur@66560, bsums@131072
#define OFF_PERM    30408704u    // 4 MB: perm[newid] = oldid
#define OFF_PACKA   34603008u    // 4 MB: (rowptr_orig | deg<<24) in perm order
#define OFF_SCANP   38797312u    // 4 MB: exclusive scan of deg in perm order
#define OFF_ESRCP   42991616u    // 16 MB: EE ints, compact perm-CSR, values = inv[src]
#define OFF_HA      59768832u    // 32 MB (57 MB)
#define OFF_HB      93323264u    // 32 MB (89 MB)
#define OFF_EBUF    59768832u    // 40 MB, aliases hA+hB head; dead after k_csr
#define OFF_XP      93323264u    // 12 MB, aliases hB; dead after layer1 (hB written at conv2)
#define OFF_INV     105906176u   // 4 MB, aliases hB tail; dead after k_edgecopy
#define SS 384                   // stats slot stride (floats): 24 counters * 16

// ================= init =================
__global__ void k_init(int* __restrict__ cursor, float* __restrict__ stats,
                       int* __restrict__ classcnt){
  int t = threadIdx.x;
  cursor[t] = t * CAP;
  if(t < NCLS) classcnt[t] = 0;
  for(int i = t; i < 10*SS; i += 256) stats[i] = 0.0f;
}

// ============ pass B: bin edges into 256 buckets by dst>>12 ============
__global__ void k_bucket(const int* __restrict__ src, const int* __restrict__ dst,
                         int* __restrict__ cursor, int2* __restrict__ ebuf){
  __shared__ int hist[NBUCK];
  __shared__ int base[NBUCK];
  int t = threadIdx.x;
  hist[t] = 0;
  __syncthreads();
  int eb = blockIdx.x * 4096;
  int s[16], d[16], r[16];
#pragma unroll
  for(int k=0; k<16; k++){
    int e = eb + k*256 + t;
    s[k] = src[e];
    d[k] = dst[e];
    r[k] = atomicAdd(&hist[d[k] >> 12], 1);
  }
  __syncthreads();
  base[t] = atomicAdd(&cursor[t], hist[t]);
  __syncthreads();
#pragma unroll
  for(int k=0; k<16; k++){
    int b = d[k] >> 12;
    int pos = base[b] + r[k];
    if(pos < (b+1)*CAP)                 // capacity guard
      ebuf[pos] = make_int2(s[k], d[k]);
  }
}

// ===== pass C: per-bucket counting sort -> rowptr/rowend/ssrc =====
__global__ void k_csr(const int2* __restrict__ ebuf, const int* __restrict__ cursor,
                      int* __restrict__ ssrc, int* __restrict__ rowptr,
                      int* __restrict__ rowend){
  __shared__ int hist[BNODES];
  __shared__ int part[256];
  int b = blockIdx.x, t = threadIdx.x;
  int cnt = cursor[b] - b*CAP;
  if(cnt > CAP) cnt = CAP;
  int ebase = b*CAP;
  for(int i=t; i<BNODES; i+=256) hist[i] = 0;
  __syncthreads();
  for(int i=t; i<cnt; i+=256){
    int2 e = ebuf[ebase + i];
    atomicAdd(&hist[e.y & (BNODES-1)], 1);
  }
  __syncthreads();
  int loc[16]; int sum = 0;
#pragma unroll
  for(int j=0; j<16; j++){ loc[j] = hist[t*16 + j]; sum += loc[j]; }
  part[t] = sum;
  __syncthreads();
#pragma unroll
  for(int off=1; off<256; off<<=1){
    int v = (t >= off) ? part[t-off] : 0;
    __syncthreads();
    part[t] += v;
    __syncthreads();
  }
  int run = part[t] - sum;
#pragma unroll
  for(int j=0; j<16; j++){
    int n = b*BNODES + t*16 + j;
    rowptr[n] = ebase + run;
    rowend[n] = ebase + run + loc[j];
    hist[t*16 + j] = run;
    run += loc[j];
  }
  __syncthreads();
  for(int i=t; i<cnt; i+=256){
    int2 e = ebuf[ebase + i];
    int pos = atomicAdd(&hist[e.y & (BNODES-1)], 1);
    ssrc[ebase + pos] = e.x;
  }
}

// ===== degree-class histogram =====
__global__ void k_classhist(const int* __restrict__ rowptr, const int* __restrict__ rowend,
                            int* __restrict__ classcnt){
  __shared__ int lh[NCLS];
  int t = threadIdx.x;
  if(t < NCLS) lh[t] = 0;
  __syncthreads();
  int4 rp = ((const int4*)rowptr)[blockIdx.x*256 + t];
  int4 re = ((const int4*)rowend)[blockIdx.x*256 + t];
  int c0 = min(re.x-rp.x, NCLS-1), c1 = min(re.y-rp.y, NCLS-1);
  int c2 = min(re.z-rp.z, NCLS-1), c3 = min(re.w-rp.w, NCLS-1);
  atomicAdd(&lh[c0],1); atomicAdd(&lh[c1],1);
  atomicAdd(&lh[c2],1); atomicAdd(&lh[c3],1);
  __syncthreads();
  if(t < NCLS && lh[t]) atomicAdd(&classcnt[t], lh[t]);
}

// ===== exclusive scan of 64 class counts -> classcur =====
__global__ void k_classscan(const int* __restrict__ classcnt, int* __restrict__ classcur){
  if(threadIdx.x == 0){
    int acc = 0;
    for(int i=0; i<NCLS; i++){ classcur[i] = acc; acc += classcnt[i]; }
  }
}

// ===== scatter nodes into degree-sorted permutation =====
__global__ void k_permscatter(const int* __restrict__ rowptr, const int* __restrict__ rowend,
                              int* __restrict__ classcur,
                              int* __restrict__ perm, int* __restrict__ inv,
                              unsigned* __restrict__ packA){
  __shared__ int lh[NCLS], lb[NCLS];
  int t = threadIdx.x;
  int i = blockIdx.x*256 + t;
  int rp = rowptr[i], deg = rowend[i] - rp;
  int c = min(deg, NCLS-1);
  if(t < NCLS) lh[t] = 0;
  __syncthreads();
  int r = atomicAdd(&lh[c], 1);
  __syncthreads();
  if(t < NCLS) lb[t] = lh[t] ? atomicAdd(&classcur[t], lh[t]) : 0;
  __syncthreads();
  int pos = lb[c] + r;
  perm[pos] = i;
  inv[i] = pos;
  packA[pos] = (unsigned)rp | ((unsigned)min(deg,255) << 24);
}

// ===== 3-kernel exclusive scan of degrees (perm order) -> scanPtr =====
__global__ void k_scanP1(const unsigned* __restrict__ packA, int* __restrict__ scanPtr,
                         int* __restrict__ bsums){
  __shared__ int lds[256];
  int b = blockIdx.x, t = threadIdx.x;
  uint4 v = ((const uint4*)packA)[b*256 + t];
  int d0 = v.x>>24, d1 = v.y>>24, d2 = v.z>>24, d3 = v.w>>24;
  int s0 = d0, s1 = s0+d1, s2 = s1+d2, s3 = s2+d3;
  lds[t] = s3; __syncthreads();
#pragma unroll
  for(int off=1; off<256; off<<=1){
    int u = (t >= off) ? lds[t-off] : 0;
    __syncthreads();
    lds[t] += u;
    __syncthreads();
  }
  int excl = lds[t] - s3;
  int4 o; o.x = excl; o.y = excl + s0; o.z = excl + s1; o.w = excl + s2;
  ((int4*)scanPtr)[b*256 + t] = o;
  if(t == 255) bsums[b] = lds[255];
}

__global__ void k_scanP2(int* __restrict__ bsums){
  __shared__ int lds[256];
  int t = threadIdx.x;
  int4 d = ((int4*)bsums)[t];
  int s0 = d.x, s1 = s0+d.y, s2 = s1+d.z, s3 = s2+d.w;
  lds[t] = s3; __syncthreads();
#pragma unroll
  for(int off=1; off<256; off<<=1){
    int v = (t >= off) ? lds[t-off] : 0;
    __syncthreads();
    lds[t] += v;
    __syncthreads();
  }
  int excl = lds[t] - s3;
  int4 o; o.x = excl; o.y = excl + s0; o.z = excl + s1; o.w = excl + s2;
  ((int4*)bsums)[t] = o;
}

__global__ void k_scanP3(const int* __restrict__ bsums, int* __restrict__ scanPtr){
  int i = blockIdx.x*blockDim.x + threadIdx.x;
  scanPtr[i] += bsums[i >> 10];
}

// ===== permute x into perm space =====
__global__ void k_xperm(const float* __restrict__ x, const int* __restrict__ perm,
                        float* __restrict__ xP){
  int t = blockIdx.x*256 + threadIdx.x;
  int i = perm[t];
  xP[3*t] = x[3*i]; xP[3*t+1] = x[3*i+1]; xP[3*t+2] = x[3*i+2];
}

// ===== copy edges into compact perm-CSR, translating src -> inv[src] =====
__global__ void k_edgecopy(const unsigned* __restrict__ packA, const int* __restrict__ scanPtr,
                           const int* __restrict__ ssrc, const int* __restrict__ inv,
                           int* __restrict__ esrcP){
  int t = blockIdx.x*256 + threadIdx.x;
  unsigned pk = packA[t];
  int op = pk & 0xFFFFFF;
  int d  = pk >> 24;
  int sp = scanPtr[t];
  for(int j=0; j<d; j++) esrcP[sp+j] = inv[ssrc[op+j]];
}

// ================= stats helpers =================
template<int NF>
__device__ __forceinline__ void stats_flush(float* ssum, float* ssq,
                                            float* __restrict__ stats_out){
  __shared__ float sred[2*NF];
#pragma unroll
  for(int f=0; f<NF; f++){
    float a = ssum[f], b = ssq[f];
#pragma unroll
    for(int off=1; off<64; off<<=1){
      a += __shfl_xor(a, off, 64);
      b += __shfl_xor(b, off, 64);
    }
    ssum[f] = a; ssq[f] = b;
  }
  if(threadIdx.x < 2*NF) sred[threadIdx.x] = 0.0f;
  __syncthreads();
  if((threadIdx.x & 63) == 0){
#pragma unroll
    for(int f=0; f<NF; f++){
      atomicAdd(&sred[f],      ssum[f]);
      atomicAdd(&sred[NF + f], ssq[f]);
    }
  }
  __syncthreads();
  if(threadIdx.x < 2*NF)
    atomicAdd(&stats_out[threadIdx.x * 16], sred[threadIdx.x]);
}

__device__ __forceinline__ void store_row16(_Float16* __restrict__ hout, int i,
                                            const float* ov){
  half8 o0, o1;
#pragma unroll
  for(int j=0; j<8; j++) o0[j] = (_Float16)ov[j];
#pragma unroll
  for(int j=0; j<4; j++) o1[j] = (_Float16)ov[8+j];
  o1[4]=(_Float16)0.f; o1[5]=(_Float16)0.f; o1[6]=(_Float16)0.f; o1[7]=(_Float16)0.f;
  half8* op = (half8*)(hout + 16*i);
  op[0] = o0; op[1] = o1;
}

// ===== conv layer 1 (perm space, degree-uniform waves): xP[N,3] -> hA[N,16] =====
__global__ __launch_bounds__(256) void
k_layer1(const float* __restrict__ xP,
         const int* __restrict__ scanPtr, const unsigned* __restrict__ packA,
         const int* __restrict__ esrcP,
         const float* __restrict__ Wl1, const float* __restrict__ Wr1,
         const float* __restrict__ b1,
         _Float16* __restrict__ hout, float* __restrict__ stats_out){
  int t = blockIdx.x*256 + threadIdx.x;
  int st = scanPtr[t];
  int deg = packA[t] >> 24;
  int en = st + deg;
  float a0=0.f, a1=0.f, a2=0.f;
  int p = st;
  for(; p+4 <= en; p += 4){
    int s0=esrcP[p], s1=esrcP[p+1], s2=esrcP[p+2], s3=esrcP[p+3];
    float u0=xP[3*s0], u1=xP[3*s0+1], u2=xP[3*s0+2];
    float v0=xP[3*s1], v1=xP[3*s1+1], v2=xP[3*s1+2];
    float w0=xP[3*s2], w1=xP[3*s2+1], w2=xP[3*s2+2];
    float y0=xP[3*s3], y1=xP[3*s3+1], y2=xP[3*s3+2];
    a0 += u0+v0+w0+y0; a1 += u1+v1+w1+y1; a2 += u2+v2+w2+y2;
  }
  for(; p<en; p++){
    int s = esrcP[p];
    a0 += xP[3*s]; a1 += xP[3*s+1]; a2 += xP[3*s+2];
  }
  float inv = (deg > 0) ? 1.0f/(float)deg : 0.0f;
  a0 *= inv; a1 *= inv; a2 *= inv;
  float x0 = xP[3*t], x1 = xP[3*t+1], x2 = xP[3*t+2];
  float ssum[12], ssq[12], ov[12];
#pragma unroll
  for(int f=0; f<12; f++){
    float o = b1[f]
            + Wl1[3*f]*a0 + Wl1[3*f+1]*a1 + Wl1[3*f+2]*a2
            + Wr1[3*f]*x0 + Wr1[3*f+1]*x1 + Wr1[3*f+2]*x2;
    o = fmaxf(o, 0.0f);
    ov[f] = o; ssum[f] = o; ssq[f] = o*o;
  }
  store_row16(hout, t, ov);
  stats_flush<12>(ssum, ssq, stats_out);
}

// ===== conv layers 2..8 (perm space): BN folded + SAGE, fp16 -> fp16 =====
template<bool STATS>
__global__ __launch_bounds__(256) void
k_layerk(const _Float16* __restrict__ hin,
         const int* __restrict__ scanPtr, const unsigned* __restrict__ packA,
         const int* __restrict__ esrcP,
         const float* __restrict__ Wl, const float* __restrict__ Wr,
         const float* __restrict__ bias,
         const float* __restrict__ bng, const float* __restrict__ bnb,
         const float* __restrict__ stats_in,
         _Float16* __restrict__ hout, float* __restrict__ stats_out){
  float sc[12], sh[12];
#pragma unroll
  for(int f=0; f<12; f++){
    float m = stats_in[f*16]      * (1.0f/NN);
    float v = stats_in[(12+f)*16] * (1.0f/NN) - m*m;
    float is = rsqrtf(v + BN_EPS);
    sc[f] = bng[f]*is;
    sh[f] = bnb[f] - m*sc[f];
  }
  int t = blockIdx.x*256 + threadIdx.x;
  int st = scanPtr[t];
  int deg = packA[t] >> 24;
  int en = st + deg;
  float s[12];
#pragma unroll
  for(int k=0; k<12; k++) s[k]=0.f;
  int p = st;
  for(; p+4 <= en; p += 4){
    int s0=esrcP[p], s1=esrcP[p+1], s2=esrcP[p+2], s3=esrcP[p+3];
    const half8* p0 = (const half8*)(hin + 16*s0);
    const half8* p1 = (const half8*)(hin + 16*s1);
    const half8* p2 = (const half8*)(hin + 16*s2);
    const half8* p3 = (const half8*)(hin + 16*s3);
    half8 a0=p0[0], a1=p0[1];
    half8 b0=p1[0], b1=p1[1];
    half8 c0=p2[0], c1=p2[1];
    half8 d0=p3[0], d1=p3[1];
#pragma unroll
    for(int k=0; k<8; k++)
      s[k] += ((float)a0[k] + (float)b0[k]) + ((float)c0[k] + (float)d0[k]);
#pragma unroll
    for(int k=0; k<4; k++)
      s[8+k] += ((float)a1[k] + (float)b1[k]) + ((float)c1[k] + (float)d1[k]);
  }
  for(; p<en; p++){
    int sid = esrcP[p];
    const half8* hp = (const half8*)(hin + 16*sid);
    half8 q0 = hp[0], q1 = hp[1];
#pragma unroll
    for(int k=0; k<8; k++) s[k] += (float)q0[k];
#pragma unroll
    for(int k=0; k<4; k++) s[8+k] += (float)q1[k];
  }
  float inv   = (deg > 0) ? 1.0f/(float)deg : 0.0f;
  float zmask = (deg > 0) ? 1.0f : 0.0f;
  const half8* hp = (const half8*)(hin + 16*t);
  half8 r0 = hp[0], r1 = hp[1];
  float hi[12];
#pragma unroll
  for(int k=0; k<8; k++) hi[k] = (float)r0[k];
#pragma unroll
  for(int k=0; k<4; k++) hi[8+k] = (float)r1[k];
  float aggn[12], hn[12];
#pragma unroll
  for(int k=0; k<12; k++){
    aggn[k] = (s[k]*inv*sc[k] + sh[k]) * zmask;  // BN-of-mean; deg=0 -> 0
    hn[k]   = hi[k]*sc[k] + sh[k];
  }
  float ssum[12], ssq[12], ov[12];
#pragma unroll
  for(int f=0; f<12; f++){
    float o = bias[f];
#pragma unroll
    for(int k=0; k<12; k++) o += Wl[12*f+k]*aggn[k];
#pragma unroll
    for(int k=0; k<12; k++) o += Wr[12*f+k]*hn[k];
    o = fmaxf(o, 0.0f);
    ov[f] = o;
    ssum[f] = o; ssq[f] = o*o;
  }
  store_row16(hout, t, ov);
  if(STATS) stats_flush<12>(ssum, ssq, stats_out);
}

// ========== head linear on [2N,6] stored as padded fp16 [N,16] (perm space) ==========
template<bool FIRST>
__global__ void k_head(const _Float16* __restrict__ zin,
                       const float* __restrict__ W, const float* __restrict__ bv,
                       const float* __restrict__ g6, const float* __restrict__ b6,
                       const float* __restrict__ stats_in,
                       _Float16* __restrict__ zout, float* __restrict__ stats_out){
  float sc[6], sh[6];
  if(!FIRST){
#pragma unroll
    for(int k=0; k<6; k++){
      float m = stats_in[k*16]     * (1.0f/(2.0f*NN));
      float v = stats_in[(6+k)*16] * (1.0f/(2.0f*NN)) - m*m;
      float is = rsqrtf(v + BN_EPS);
      sc[k] = g6[k]*is;
      sh[k] = b6[k] - m*sc[k];
    }
  }
  float ssum[6], ssq[6];
#pragma unroll
  for(int f=0; f<6; f++){ ssum[f]=0.f; ssq[f]=0.f; }
  int stride = gridDim.x*blockDim.x;
  for(int i = blockIdx.x*blockDim.x + threadIdx.x; i < NN; i += stride){
    const half8* zp = (const half8*)(zin + 16*i);
    half8 a = zp[0], b = zp[1];
    float t0[6] = {(float)a[0],(float)a[1],(float)a[2],(float)a[3],(float)a[4],(float)a[5]};
    float t1[6] = {(float)a[6],(float)a[7],(float)b[0],(float)b[1],(float)b[2],(float)b[3]};
    if(!FIRST){
#pragma unroll
      for(int k=0; k<6; k++){
        t0[k] = fmaxf(t0[k]*sc[k] + sh[k], 0.0f);
        t1[k] = fmaxf(t1[k]*sc[k] + sh[k], 0.0f);
      }
    }
    float ov[12];
#pragma unroll
    for(int f=0; f<6; f++){
      float o0 = bv[f], o1 = bv[f];
#pragma unroll
      for(int k=0; k<6; k++){ o0 += W[6*f+k]*t0[k]; o1 += W[6*f+k]*t1[k]; }
      ov[f] = o0; ov[6+f] = o1;
      ssum[f] += o0 + o1; ssq[f] += o0*o0 + o1*o1;
    }
    store_row16(zout, i, ov);
  }
  stats_flush<6>(ssum, ssq, stats_out);
}

// ========== final: BN+ReLU + Linear(6,1) + sigmoid; un-permute on store ==========
__global__ void k_out(const _Float16* __restrict__ zin, const int* __restrict__ perm,
                      const float* __restrict__ g6, const float* __restrict__ b6,
                      const float* __restrict__ stats_in,
                      const float* __restrict__ outW, const float* __restrict__ outb,
                      float* __restrict__ out){
  float sc[6], sh[6], w[6];
#pragma unroll
  for(int k=0; k<6; k++){
    float m = stats_in[k*16]     * (1.0f/(2.0f*NN));
    float v = stats_in[(6+k)*16] * (1.0f/(2.0f*NN)) - m*m;
    float is = rsqrtf(v + BN_EPS);
    sc[k] = g6[k]*is;
    sh[k] = b6[k] - m*sc[k];
    w[k] = outW[k];
  }
  float ob = outb[0];
  int stride = gridDim.x*blockDim.x;
  for(int i = blockIdx.x*blockDim.x + threadIdx.x; i < NN; i += stride){
    const half8* zp = (const half8*)(zin + 16*i);
    half8 a = zp[0], b = zp[1];
    float t0[6] = {(float)a[0],(float)a[1],(float)a[2],(float)a[3],(float)a[4],(float)a[5]};
    float t1[6] = {(float)a[6],(float)a[7],(float)b[0],(float)b[1],(float)b[2],(float)b[3]};
    float o0 = ob, o1 = ob;
#pragma unroll
    for(int k=0; k<6; k++){
      o0 += w[k] * fmaxf(t0[k]*sc[k] + sh[k], 0.0f);
      o1 += w[k] * fmaxf(t1[k]*sc[k] + sh[k], 0.0f);
    }
    float2 r;
    r.x = 1.0f / (1.0f + expf(-o0));
    r.y = 1.0f / (1.0f + expf(-o1));
    ((float2*)out)[perm[i]] = r;   // node perm[i] -> out rows 2p, 2p+1
  }
}

extern "C" void kernel_launch(void* const* d_in, const int* in_sizes, int n_in,
                              void* d_out, int out_size, void* d_ws, size_t ws_size,
                              hipStream_t stream){
  const float* x    = (const float*)d_in[0];
  const int*   ei   = (const int*)  d_in[1];
  const float* Wl1  = (const float*)d_in[2];
  const float* Wr1  = (const float*)d_in[3];
  const float* b1   = (const float*)d_in[4];
  const float* Wl   = (const float*)d_in[5];
  const float* Wr   = (const float*)d_in[6];
  const float* bb   = (const float*)d_in[7];
  const float* bng  = (const float*)d_in[8];
  const float* bnb  = (const float*)d_in[9];
  const float* linW = (const float*)d_in[10];
  const float* linb = (const float*)d_in[11];
  const float* bn6g = (const float*)d_in[12];
  const float* bn6b = (const float*)d_in[13];
  const float* outW = (const float*)d_in[14];
  const float* outb = (const float*)d_in[15];
  float* out = (float*)d_out;

  char* ws = (char*)d_ws;
  int*      ssrc    = (int*)     (ws + OFF_SSRC);
  int*      rowptr  = (int*)     (ws + OFF_ROWPTR);
  int*      rowend  = (int*)     (ws + OFF_ROWEND);
  int*      cursor  = (int*)     (ws + OFF_MISC);
  float*    stats   = (float*)   (ws + OFF_MISC + 4096);
  int*      classcnt= (int*)     (ws + OFF_MISC + 65536);
  int*      classcur= (int*)     (ws + OFF_MISC + 66560);
  int*      bsums   = (int*)     (ws + OFF_MISC + 131072);
  int*      perm    = (int*)     (ws + OFF_PERM);
  unsigned* packA   = (unsigned*)(ws + OFF_PACKA);
  int*      scanPtr = (int*)     (ws + OFF_SCANP);
  int*      esrcP   = (int*)     (ws + OFF_ESRCP);
  _Float16* hA      = (_Float16*)(ws + OFF_HA);
  _Float16* hB      = (_Float16*)(ws + OFF_HB);
  int2*     ebuf    = (int2*)    (ws + OFF_EBUF);  // dead after k_csr
  float*    xP      = (float*)   (ws + OFF_XP);    // dead after layer1
  int*      inv     = (int*)     (ws + OFF_INV);   // dead after k_edgecopy

  const int* srcp = ei;
  const int* dstp = ei + EE;

  // ---- graph build + degree-sorted relabel (one-time per call) ----
  k_init       <<<1,    256, 0, stream>>>(cursor, stats, classcnt);
  k_bucket     <<<1024, 256, 0, stream>>>(srcp, dstp, cursor, ebuf);
  k_csr        <<<NBUCK,256, 0, stream>>>(ebuf, cursor, ssrc, rowptr, rowend);
  k_classhist  <<<1024, 256, 0, stream>>>(rowptr, rowend, classcnt);
  k_classscan  <<<1,    64,  0, stream>>>(classcnt, classcur);
  k_permscatter<<<4096, 256, 0, stream>>>(rowptr, rowend, classcur, perm, inv, packA);
  k_scanP1     <<<1024, 256, 0, stream>>>(packA, scanPtr, bsums);
  k_scanP2     <<<1,    256, 0, stream>>>(bsums);
  k_scanP3     <<<4096, 256, 0, stream>>>(bsums, scanPtr);
  k_xperm      <<<4096, 256, 0, stream>>>(x, perm, xP);
  k_edgecopy   <<<4096, 256, 0, stream>>>(packA, scanPtr, ssrc, inv, esrcP);

  // ---- conv1 (stats -> slot 0) ----
  k_layer1<<<4096, 256, 0, stream>>>(xP, scanPtr, packA, esrcP, Wl1, Wr1, b1, hA, stats);

  // ---- conv2..conv8 ----
  _Float16* hi = hA; _Float16* ho = hB;
  for(int l=0; l<7; l++){
    const float* st_in = stats + l*SS;
    float* st_out      = stats + (l+1)*SS;
    if(l < 6)
      k_layerk<true><<<4096, 256, 0, stream>>>(hi, scanPtr, packA, esrcP,
        Wl + 144*l, Wr + 144*l, bb + 12*l, bng + 12*l, bnb + 12*l, st_in, ho, st_out);
    else
      k_layerk<false><<<4096, 256, 0, stream>>>(hi, scanPtr, packA, esrcP,
        Wl + 144*l, Wr + 144*l, bb + 12*l, bng + 12*l, bnb + 12*l, st_in, ho, st_out);
    _Float16* t = hi; hi = ho; ho = t;
  }

  // ---- head (perm space; BN stats order-invariant) ----
  k_head<true> <<<2048, 256, 0, stream>>>(hi, linW, linb, bn6g, bn6b,
                                          stats + 7*SS, ho, stats + 7*SS);
  { _Float16* t = hi; hi = ho; ho = t; }
  k_head<false><<<2048, 256, 0, stream>>>(hi, linW, linb, bn6g, bn6b,
                                          stats + 7*SS, ho, stats + 8*SS);
  { _Float16* t = hi; hi = ho; ho = t; }
  k_head<false><<<2048, 256, 0, stream>>>(hi, linW, linb, bn6g, bn6b,
                                          stats + 8*SS, ho, stats + 9*SS);
  { _Float16* t = hi; hi = ho; ho = t; }
  k_out<<<2048, 256, 0, stream>>>(hi, perm, bn6g, bn6b, stats + 9*SS, outW, outb, out);
}